// Round 9
// baseline (32.652 us; speedup 1.0000x reference)
//
#include <hip/hip_runtime.h>
#include <hip/hip_bf16.h>

namespace {

// may_alias: LDS is written as u64 (bf16x4 packs) and read as bf16x8.
typedef short bf16x8 __attribute__((ext_vector_type(8), may_alias));
typedef unsigned long long u64_ma __attribute__((may_alias));
typedef __attribute__((ext_vector_type(16))) float f32x16;   // MFMA 32x32 acc

constexpr int kB = 32, kT = 16384, kCin = 32, kCout = 32;
constexpr int kL = 128;            // owned rows per chunk
constexpr int kK = 32;             // zero-state warm-up
constexpr int kChunks = kT / kL;   // 128
constexpr int kWpB = 4;            // waves per block
constexpr int kRS = 80;            // LDS bf16 row stride: 64B data + 16B pad
constexpr int kStageRows = 34;     // 32 rows + 2 halo rows
constexpr int kStageB = kStageRows * kRS;  // 2720 B per stage
constexpr int kNT = 5;             // tiles per unit (1 warm-up + 4 owned), all chunks

__device__ __forceinline__ unsigned bfbits(float f) {
  return (unsigned)__builtin_bit_cast(unsigned short, __float2bfloat16(f));
}

// Wave = TWO independent (b, chunk) units (chunks c and c+64, same b):
// doubled ILP per wave (2 prefetch streams, 2 interleaved IIR chains) to fill
// the stall gaps that TLP at 4 waves/SIMD provably (R5==R8) didn't fill.
__global__ __launch_bounds__(256, 2) void mimo_mfma6(
    const float* __restrict__ u,        // [B, T, CIN]
    const float* __restrict__ x0,       // [B, 2, COUT]
    const float* __restrict__ a_coeff,  // [2, COUT]
    const float* __restrict__ b_coeff,  // [3, CIN, COUT]
    float* __restrict__ out)            // [B, T, COUT]
{
  __shared__ char lds[kWpB][2][kStageB];   // 21.3 KiB per block

  const int tidx = (int)threadIdx.x;
  const int lane = tidx & 63;
  const int col  = lane & 31;          // output channel / time-row within tile
  const int g    = lane >> 5;          // lane-half (k-slot group / C-row +4)
  const int widx = tidx >> 6;
  const int wid  = (int)blockIdx.x * kWpB + widx;   // 0..2047
  const int b  = wid >> 6;             // 0..31
  const int c  = wid & 63;             // unit A chunk; unit B chunk = c + 64
  const int t0A = c * kL;
  const int t0B = (c + 64) * kL;
  const int tstartA = t0A - kK;        // unified: chunk 0 warms over zero-pad
  const int tstartB = t0B - kK;

  char* LwA = &lds[widx][0][0];
  char* LwB = &lds[widx][1][0];

  // B fragments: slot (g,j) of K-step (tau,h) = b_coeff[2-tau][16g+8h+j][col].
  // A uses the SAME slot->channel map, so the HW k-order cancels.
  bf16x8 Bf[3][2];
#pragma unroll
  for (int tau = 0; tau < 3; ++tau)
#pragma unroll
    for (int h = 0; h < 2; ++h) {
      const float* bp = b_coeff + (size_t)(2 - tau) * kCin * kCout
                        + (16 * g + 8 * h) * kCout + col;
      bf16x8 fr;
#pragma unroll
      for (int j = 0; j < 8; ++j)
        fr[j] = (short)__builtin_bit_cast(unsigned short, __float2bfloat16(bp[j * kCout]));
      Bf[tau][h] = fr;
    }

  const float a1 = a_coeff[col];
  const float a2 = a_coeff[kCout + col];
  // chunk-0 exact state (only unit A can be chunk 0); injected at tbase==t0.
  float i1 = 0.f, i2 = 0.f;
  if (c == 0) {
    i1 = x0[(b * 2 + 1) * kCout + col];
    i2 = x0[(b * 2 + 0) * kCout + col];
  }
  float s1A = 0.f, s2A = 0.f, s1B = 0.f, s2B = 0.f;

  const float* ub = u + (size_t)b * kT * kCin;
  float* ob = out + (size_t)b * kT * kCout;

  // Coalesced stage load: f4-index f of a 34-row stage starting at rowbase.
  auto gload = [&](int rowbase, int f) -> float4 {
    const int grow = rowbase + (f >> 3);
    if (grow >= 0)
      return *(const float4*)(ub + (size_t)grow * kCin + ((f & 7) << 2));
    float4 z; z.x = 0.f; z.y = 0.f; z.z = 0.f; z.w = 0.f;
    return z;
  };
  // cvt f32x4 -> bf16x4 and ds_write_b64 into the 80B-stride stage.
  auto stash = [&](char* Lw, int f, float4 v) {
    const unsigned lo = bfbits(v.x) | (bfbits(v.y) << 16);
    const unsigned hi = bfbits(v.z) | (bfbits(v.w) << 16);
    const unsigned long long q = ((unsigned long long)hi << 32) | lo;
    *(u64_ma*)(Lw + (f >> 3) * kRS + (f & 7) * 8) = q;
  };

  // -------- prologue: stage tile 0 of both units --------
  {
    const int rbA = tstartA - 2, rbB = tstartB - 2;
    float4 a0 = gload(rbA, lane);
    float4 a1v = gload(rbA, lane + 64);
    float4 a2v = gload(rbA, lane + 128);
    float4 a3 = gload(rbA, lane + 192);
    float4 b0 = gload(rbB, lane);
    float4 b1 = gload(rbB, lane + 64);
    float4 b2 = gload(rbB, lane + 128);
    float4 b3 = gload(rbB, lane + 192);
    float4 a4, b4;
    if (lane < 16) { a4 = gload(rbA, lane + 256); b4 = gload(rbB, lane + 256); }
    stash(LwA, lane, a0);       stash(LwB, lane, b0);
    stash(LwA, lane + 64, a1v); stash(LwB, lane + 64, b1);
    stash(LwA, lane + 128, a2v); stash(LwB, lane + 128, b2);
    stash(LwA, lane + 192, a3); stash(LwB, lane + 192, b3);
    if (lane < 16) { stash(LwA, lane + 256, a4); stash(LwB, lane + 256, b4); }
  }
  asm volatile("" ::: "memory");   // stage writes ordered before tile-0 reads

  for (int tile = 0; tile < kNT; ++tile) {
    const int tbaseA = tstartA + 32 * tile;
    const int tbaseB = tstartB + 32 * tile;
    const bool last = (tile + 1 == kNT);

    // issue-early: both units' next-stage loads fly during this tile's compute.
    float4 nA0, nA1, nA2, nA3, nA4, nB0, nB1, nB2, nB3, nB4;
    if (!last) {
      const int rbA = tbaseA + 30, rbB = tbaseB + 30;
      nA0 = gload(rbA, lane);       nB0 = gload(rbB, lane);
      nA1 = gload(rbA, lane + 64);  nB1 = gload(rbB, lane + 64);
      nA2 = gload(rbA, lane + 128); nB2 = gload(rbB, lane + 128);
      nA3 = gload(rbA, lane + 192); nB3 = gload(rbB, lane + 192);
      if (lane < 16) { nA4 = gload(rbA, lane + 256); nB4 = gload(rbB, lane + 256); }
    }

    // ---- FIR both units: 6x ds_read_b128 + 6 MFMAs each ----
    f32x16 accA, accB;
#pragma unroll
    for (int i = 0; i < 16; ++i) { accA[i] = 0.f; accB[i] = 0.f; }
#pragma unroll
    for (int tau = 0; tau < 3; ++tau) {
      const char* rpA = LwA + (col + tau) * kRS + 32 * g;
      const char* rpB = LwB + (col + tau) * kRS + 32 * g;
#pragma unroll
      for (int h = 0; h < 2; ++h) {
        const bf16x8 faA = *(const bf16x8*)(rpA + 16 * h);
        const bf16x8 faB = *(const bf16x8*)(rpB + 16 * h);
        accA = __builtin_amdgcn_mfma_f32_32x32x16_bf16(faA, Bf[tau][h], accA, 0, 0, 0);
        accB = __builtin_amdgcn_mfma_f32_32x32x16_bf16(faB, Bf[tau][h], accB, 0, 0, 0);
      }
    }

    // ---- full-acc half exchange: 32 independent shuffles ----
    float othA[16], othB[16];
#pragma unroll
    for (int i = 0; i < 16; ++i) {
      othA[i] = __shfl_xor(accA[i], 32);
      othB[i] = __shfl_xor(accB[i], 32);
    }

    // chunk-0 exact state injection (warm-up over zero-pad left state at 0).
    if (c == 0 && tbaseA == t0A) { s1A = i1; s2A = i2; }

    // ---- IIR: two independent chains interleaved (ILP=2) ----
    // C/D layout: reg r (half gg) holds row (r&3) + 8*(r>>2) + 4*gg.
    const bool ownedA = (tbaseA >= t0A);
    const bool ownedB = (tbaseB >= t0B);
    float x1A = s1A, x2A = s2A, x1B = s1B, x2B = s2B;
#pragma unroll
    for (int j = 0; j < 32; ++j) {
      const int reg = 4 * (j >> 3) + (j & 3);
      const int g4  = (j >> 2) & 1;
      const float vA = (g4 == g) ? accA[reg] : othA[reg];
      const float vB = (g4 == g) ? accB[reg] : othB[reg];
      const float xnA = fmaf(a1, x1A, fmaf(a2, x2A, vA));
      const float xnB = fmaf(a1, x1B, fmaf(a2, x2B, vB));
      if (ownedA && g4 == g) ob[(size_t)(tbaseA + j) * kCout + col] = xnA;
      if (ownedB && g4 == g) ob[(size_t)(tbaseB + j) * kCout + col] = xnB;
      x2A = x1A; x1A = xnA;
      x2B = x1B; x1B = xnB;
    }
    s1A = x1A; s2A = x2A; s1B = x1B; s2B = x2B;

    // write-late: refill both stage buffers (order pinned by barriers; the
    // wave-local LDS FIFO executes DS ops in issue order).
    if (!last) {
      asm volatile("" ::: "memory");   // this tile's ds_reads issue first
      stash(LwA, lane, nA0);       stash(LwB, lane, nB0);
      stash(LwA, lane + 64, nA1);  stash(LwB, lane + 64, nB1);
      stash(LwA, lane + 128, nA2); stash(LwB, lane + 128, nB2);
      stash(LwA, lane + 192, nA3); stash(LwB, lane + 192, nB3);
      if (lane < 16) { stash(LwA, lane + 256, nA4); stash(LwB, lane + 256, nB4); }
      asm volatile("" ::: "memory");   // refill before next tile's ds_reads
    }
  }
}

}  // namespace

extern "C" void kernel_launch(void* const* d_in, const int* in_sizes, int n_in,
                              void* d_out, int out_size, void* d_ws, size_t ws_size,
                              hipStream_t stream) {
  const float* u  = (const float*)d_in[0];
  const float* x0 = (const float*)d_in[1];
  const float* a  = (const float*)d_in[2];
  const float* bb = (const float*)d_in[3];
  float* out = (float*)d_out;

  dim3 grid(kB * (kChunks / 2) / kWpB);  // 2048 waves / 4 = 512 blocks
  dim3 block(256);
  hipLaunchKernelGGL(mimo_mfma6, grid, block, 0, stream, u, x0, a, bb, out);
}